// Round 12
// baseline (624.971 us; speedup 1.0000x reference)
//
#include <hip/hip_runtime.h>
#include <hip/hip_bf16.h>

#define B_ 8
#define C_ 64
#define N_ 4096
#define K_ 20
#define O_ 64

typedef unsigned short ushort_t;
typedef __attribute__((ext_vector_type(8))) short bf16x8;
typedef __attribute__((ext_vector_type(16))) float f32x16;

constexpr float BN_EPS = 1e-5f;
constexpr float NEG = 0.2f;
constexpr int ROWS = B_ * N_;        // 32768
constexpr int M_TOT = ROWS * K_;     // 655360

__device__ __forceinline__ float readlane_f(float v, int src) {
  return __int_as_float(__builtin_amdgcn_readlane(__float_as_int(v), src));
}

// RNE float -> bf16 bits
__device__ __forceinline__ unsigned int bf16_rne(float v) {
  unsigned int u = __float_as_uint(v);
  return (u + 0x7FFFu + ((u >> 16) & 1u)) >> 16;
}

// ----------------------------------------------------------------------------
// ws layout (float elements):
//   y   : [0,        2097152)   y[b][n][o]  = xt[b,n,:] . W1[o,:]
//   z   : [2097152,  4194304)   z[b][n][o]  = xt[b,n,:] . (W2-W1)[o,:]
//   xx  : [4194304,  4227072)   xx[b][n]    = ||xt[b,n,:]||^2
//   idx : [4227072,  4882432)   (int) idx[b][n][k]
//   s1/s2/sc/sh : [4882432, 4882688)
//   xh  : [4882688,  5931264)   bf16[b][n][c] (as ushort), high split
//   xl  : [5931264,  6979840)   bf16 mid split
//   xq  : [6979840,  8028416)   bf16 low split      (~32.1 MB total)
// ----------------------------------------------------------------------------

__global__ __launch_bounds__(256) void prep_kernel(const float* __restrict__ x,
                                                   const float* __restrict__ W,
                                                   float* __restrict__ y,
                                                   float* __restrict__ z,
                                                   float* __restrict__ xx,
                                                   ushort_t* __restrict__ xh,
                                                   ushort_t* __restrict__ xl,
                                                   ushort_t* __restrict__ xq) {
  __shared__ float xt[64][65];  // [n_local][c]
  __shared__ float w1[64][65];  // [o][c]   = W[o][c]
  __shared__ float wd[64][65];  // [o][c]   = W[o][64+c] - W[o][c]
  const int b = blockIdx.x >> 6;
  const int n0 = (blockIdx.x & 63) << 6;
  const int tid = threadIdx.x;

  for (int rep = 0; rep < 16; ++rep) {
    int id = rep * 256 + tid;
    int cc = id >> 6, nl = id & 63;
    xt[nl][cc] = x[((b * 64 + cc) << 12) + n0 + nl];  // coalesced over nl
    int o = cc, c = nl;
    float a = W[o * 128 + c];
    float bb = W[o * 128 + 64 + c];
    w1[o][c] = a;
    wd[o][c] = bb - a;
  }
  __syncthreads();

  const int o = tid & 63;
  for (int nl = tid >> 6; nl < 64; nl += 4) {
    float ay = 0.f, az = 0.f;
#pragma unroll 8
    for (int c = 0; c < 64; ++c) {
      float v = xt[nl][c];
      ay = fmaf(v, w1[o][c], ay);
      az = fmaf(v, wd[o][c], az);
    }
    int gi = (((b << 12) + n0 + nl) << 6) + o;
    y[gi] = ay;
    z[gi] = az;
  }
  if (tid < 64) {
    float s = 0.f;
#pragma unroll 8
    for (int c = 0; c < 64; ++c) {
      float v = xt[tid][c];
      s = fmaf(v, v, s);
    }
    xx[(b << 12) + n0 + tid] = s;
  }

  // 3-way bf16 split, transposed layout [b][n][c] for MFMA fragment loads
  for (int rep = 0; rep < 16; ++rep) {
    int id = rep * 256 + tid;
    int c = id & 63, nl = id >> 6;
    float v = xt[nl][c];
    unsigned int hb = bf16_rne(v);
    float hf = __uint_as_float(hb << 16);
    float r1 = v - hf;
    unsigned int lb = bf16_rne(r1);
    float lf = __uint_as_float(lb << 16);
    unsigned int qb = bf16_rne(r1 - lf);
    size_t gi = (((size_t)(b << 12) + n0 + nl) << 6) + c;  // coalesced over c
    xh[gi] = (ushort_t)hb;
    xl[gi] = (ushort_t)lb;
    xq[gi] = (ushort_t)qb;
  }
}

constexpr int ASPL = 2 * 4 * 32 * 8;  // per-split stride in Ald (ushorts)

__device__ __forceinline__ void select_tile(const float* __restrict__ dbuf,
                                            int jprev, int w, int lane,
                                            float bv[8], float T[8], int bi[8]) {
#pragma unroll
  for (int r = 0; r < 8; ++r) {
    const int row = (w << 3) + r;
#pragma unroll
    for (int seg = 0; seg < 2; ++seg) {
      float v = dbuf[row * 132 + (seg << 6) + lane];
      int jlane = jprev + (seg << 6) + lane;
      unsigned long long rem = 0xFFFFFFFFFFFFFFFFull;
      while (true) {
        unsigned long long m = __ballot(v < T[r]) & rem;
        if (!m) break;
        int src = __ffsll(m) - 1;
        rem &= ~(1ull << src);
        float cv = readlane_f(v, src);
        int cj = __builtin_amdgcn_readlane(jlane, src);
        unsigned long long le = __ballot(bv[r] <= cv) & 0xFFFFFull;
        int pos = __popcll(le);
        float pv = __shfl_up(bv[r], 1);
        int pi = __shfl_up(bi[r], 1);
        if (lane >= pos) {
          bool ins = (lane == pos);
          bv[r] = ins ? cv : pv;
          bi[r] = ins ? cj : pi;
        }
        T[r] = readlane_f(bv[r], K_ - 1);
      }
    }
  }
}

// knn v12: r11's single-barrier pipeline made spill-free.
//  - A-tile in LDS (12 KB, fragment order) with XOR bank swizzle
//    (ushort idx ^= row&24): kills the 8-way conflict of the naive layout.
//  - B loads split cc{0,1}/cc{2,3} around selection -> <=24 B VGPRs live.
//  - __launch_bounds__(256,3): cap 170 (LDS binds at 3 blocks/CU anyway),
//    so the allocator has slack -> no r11-style scratch spill.
// Per macro t: B(t) cc01 -> selection(t-1) [hides B latency] -> B(t) cc23 ->
// MFMA(t) (A from LDS per cc) -> finalize -> one barrier. Numerics and
// selection semantics identical to v8-v11 -> identical neighbor sets.
__global__ __launch_bounds__(256, 3) void knn_kernel(const ushort_t* __restrict__ xh,
                                                     const ushort_t* __restrict__ xl,
                                                     const ushort_t* __restrict__ xq,
                                                     const float* __restrict__ xx,
                                                     int* __restrict__ idx) {
  const int tid = threadIdx.x;
  const int w = tid >> 6;                 // wave 0..3
  const int lane = tid & 63;
  const int b = blockIdx.x >> 7;          // 128 strips per batch
  const int i0 = (blockIdx.x & 127) << 5; // 32-row strip
  const int mcol = lane & 31;
  const int half = lane >> 5;             // 0..1 (k-half)

  __shared__ ushort_t Ald[3 * ASPL];      // 12 KB, swizzled fragment order
  __shared__ float Dld[2][32 * 132];      // double-buffered 32x128 tile

  // ---- stage A tile (once): 3 splits x 32 rows x 64 c, swizzled ----
#pragma unroll
  for (int rep = 0; rep < 2; ++rep) {
    int id = rep * 256 + tid;             // 0..511
    const int row = id >> 4;              // 0..31
    const int c0 = (id & 15) << 2;        // 0,4,...,60
    const int hh = (c0 >> 3) & 1;
    const int cc = c0 >> 4;
    const int t0 = c0 & 7;                // 0 or 4
    const size_t g = (((size_t)(b << 12)) + i0 + row) * 64 + c0;
    int d = (hh * 4 + cc) * 256 + row * 8 + t0;
    d ^= (row & 24);                      // bank swizzle
    *(uint2*)&Ald[d] = *(const uint2*)(xh + g);
    *(uint2*)&Ald[d + ASPL] = *(const uint2*)(xl + g);
    *(uint2*)&Ald[d + 2 * ASPL] = *(const uint2*)(xq + g);
  }
  __syncthreads();

  float bv[8], T[8];
  int bi[8];
#pragma unroll
  for (int r = 0; r < 8; ++r) {
    bv[r] = __builtin_inff();
    T[r] = __builtin_inff();
    bi[r] = 0;
  }

  const float* xxb = xx + (b << 12);

  for (int t = 0; t < 32; ++t) {
    const int jb = t << 7;
    const int jw0 = jb + (w << 5);        // this wave's 32-j window
    bf16x8 Bh[4], Bl[4], Bq[4];
    const size_t bbase = (((size_t)(b << 12)) + jw0 + mcol) << 6;
#pragma unroll
    for (int cc = 0; cc < 2; ++cc) {      // first half of B (24 regs live)
      const size_t boff = bbase + cc * 16 + half * 8;
      Bh[cc] = *(const bf16x8*)(xh + boff);
      Bl[cc] = *(const bf16x8*)(xl + boff);
      Bq[cc] = *(const bf16x8*)(xq + boff);
    }
    const float xxv = xxb[jw0 + mcol];

    // ---- selection for tile t-1 (hides the B-load latency) ----
    if (t > 0) select_tile(Dld[(t - 1) & 1], (t - 1) << 7, w, lane, bv, T, bi);

#pragma unroll
    for (int cc = 2; cc < 4; ++cc) {      // second half of B
      const size_t boff = bbase + cc * 16 + half * 8;
      Bh[cc] = *(const bf16x8*)(xh + boff);
      Bl[cc] = *(const bf16x8*)(xl + boff);
      Bq[cc] = *(const bf16x8*)(xq + boff);
    }

    // ---- MFMA tile t (A fragments from swizzled LDS) ----
    f32x16 acc;
#pragma unroll
    for (int q = 0; q < 16; ++q) acc[q] = 0.f;
#pragma unroll
    for (int cc = 0; cc < 4; ++cc) {
      int ai = (half << 10) + (cc << 8) + (mcol << 3);
      ai ^= (mcol & 24);                  // matching swizzle
      bf16x8 Ah = *(const bf16x8*)&Ald[ai];
      bf16x8 Al = *(const bf16x8*)&Ald[ai + ASPL];
      bf16x8 Aq = *(const bf16x8*)&Ald[ai + 2 * ASPL];
      acc = __builtin_amdgcn_mfma_f32_32x32x16_bf16(Ah, Bh[cc], acc, 0, 0, 0);
      acc = __builtin_amdgcn_mfma_f32_32x32x16_bf16(Ah, Bl[cc], acc, 0, 0, 0);
      acc = __builtin_amdgcn_mfma_f32_32x32x16_bf16(Al, Bh[cc], acc, 0, 0, 0);
      acc = __builtin_amdgcn_mfma_f32_32x32x16_bf16(Ah, Bq[cc], acc, 0, 0, 0);
      acc = __builtin_amdgcn_mfma_f32_32x32x16_bf16(Aq, Bh[cc], acc, 0, 0, 0);
      acc = __builtin_amdgcn_mfma_f32_32x32x16_bf16(Al, Bl[cc], acc, 0, 0, 0);
    }
    float* dnew = Dld[t & 1];
#pragma unroll
    for (int q = 0; q < 16; ++q) {
      int row = (q & 3) + ((q >> 2) << 3) + (half << 2);  // verified C layout
      dnew[row * 132 + (w << 5) + mcol] = fmaf(-2.f, acc[q], xxv);
    }
    __syncthreads();
  }

  // ---- selection for the final tile ----
  select_tile(Dld[1], 31 << 7, w, lane, bv, T, bi);

#pragma unroll
  for (int r = 0; r < 8; ++r) {
    if (lane < K_) idx[((b << 12) + i0 + (w << 3) + r) * K_ + lane] = bi[r];
  }
}

__global__ __launch_bounds__(256) void stats_kernel(const float* __restrict__ y,
                                                    const float* __restrict__ z,
                                                    const int* __restrict__ idx,
                                                    float* __restrict__ s1,
                                                    float* __restrict__ s2) {
  const int tid = threadIdx.x;
  const int o = tid & 63;
  const int r = tid >> 6;
  const int row0 = blockIdx.x << 6;  // 64 rows per block
  float a1 = 0.f, a2 = 0.f;
  for (int rl = r; rl < 64; rl += 4) {
    const int row = row0 + rl;
    const int b = row >> 12;
    const float zv = z[(row << 6) + o];
    const int* ip = idx + row * K_;
    const float* yb = y + ((size_t)b << 18);
    float s1r = 0.f;
#pragma unroll
    for (int k = 0; k < K_; ++k) {
      int j = ip[k];
      float h = yb[(j << 6) + o] + zv;
      s1r += h;
      a2 = fmaf(h, h, a2);
    }
    a1 += s1r;
  }
  __shared__ float r1[4][64];
  __shared__ float r2[4][64];
  r1[r][o] = a1;
  r2[r][o] = a2;
  __syncthreads();
  if (tid < 64) {
    float t1 = r1[0][tid] + r1[1][tid] + r1[2][tid] + r1[3][tid];
    float t2 = r2[0][tid] + r2[1][tid] + r2[2][tid] + r2[3][tid];
    atomicAdd(&s1[tid], t1);
    atomicAdd(&s2[tid], t2);
  }
}

__global__ void finalize_kernel(const float* __restrict__ s1,
                                const float* __restrict__ s2,
                                const float* __restrict__ gamma,
                                const float* __restrict__ beta,
                                float* __restrict__ sc,
                                float* __restrict__ sh) {
  int o = threadIdx.x;
  float mean = s1[o] / (float)M_TOT;
  float var = s2[o] / (float)M_TOT - mean * mean;
  float inv = 1.0f / sqrtf(var + BN_EPS);
  float s = gamma[o] * inv;
  sc[o] = s;
  sh[o] = beta[o] - mean * s;
}

__global__ __launch_bounds__(256) void out_kernel(const float* __restrict__ y,
                                                  const float* __restrict__ z,
                                                  const int* __restrict__ idx,
                                                  const float* __restrict__ sc,
                                                  const float* __restrict__ sh,
                                                  float* __restrict__ out) {
  __shared__ float til[64][65];  // [o][n_local]
  const int tid = threadIdx.x;
  const int b = blockIdx.x >> 6;
  const int n0 = (blockIdx.x & 63) << 6;
  const int o = tid & 63;
  const float s = sc[o];
  const float t = sh[o];
  const float* yb = y + ((size_t)b << 18);

  for (int nl = tid >> 6; nl < 64; nl += 4) {
    const int row = (b << 12) + n0 + nl;
    const float zv = z[(row << 6) + o];
    const int* ip = idx + row * K_;
    float m = -__builtin_inff();
#pragma unroll
    for (int k = 0; k < K_; ++k) {
      int j = ip[k];
      float h = yb[(j << 6) + o] + zv;
      float hn = fmaf(h, s, t);
      float a = hn >= 0.f ? hn : NEG * hn;
      m = fmaxf(m, a);
    }
    til[o][nl] = m;
  }
  __syncthreads();
  for (int rep = 0; rep < 16; ++rep) {
    int id = rep * 256 + tid;
    int oo = id >> 6, nl = id & 63;
    out[((size_t)((b << 6) + oo) << 12) + n0 + nl] = til[oo][nl];
  }
}

extern "C" void kernel_launch(void* const* d_in, const int* in_sizes, int n_in,
                              void* d_out, int out_size, void* d_ws, size_t ws_size,
                              hipStream_t stream) {
  const float* x = (const float*)d_in[0];
  const float* W = (const float*)d_in[1];
  const float* gamma = (const float*)d_in[2];
  const float* beta = (const float*)d_in[3];
  float* ws = (float*)d_ws;
  float* y = ws;
  float* z = ws + 2097152;
  float* xx = ws + 4194304;
  int* idxp = (int*)(ws + 4227072);
  float* s1 = ws + 4882432;
  float* s2 = ws + 4882496;
  float* sc = ws + 4882560;
  float* sh = ws + 4882624;
  ushort_t* xh = (ushort_t*)(ws + 4882688);
  ushort_t* xl = (ushort_t*)(ws + 5931264);
  ushort_t* xq = (ushort_t*)(ws + 6979840);
  float* out = (float*)d_out;

  hipMemsetAsync(s1, 0, 2 * 64 * sizeof(float), stream);

  prep_kernel<<<512, 256, 0, stream>>>(x, W, y, z, xx, xh, xl, xq);
  knn_kernel<<<ROWS / 32, 256, 0, stream>>>(xh, xl, xq, xx, idxp);
  stats_kernel<<<512, 256, 0, stream>>>(y, z, idxp, s1, s2);
  finalize_kernel<<<1, 64, 0, stream>>>(s1, s2, gamma, beta, sc, sh);
  out_kernel<<<512, 256, 0, stream>>>(y, z, idxp, sc, sh, out);
}

// Round 13
// 441.138 us; speedup vs baseline: 1.4167x; 1.4167x over previous
//
#include <hip/hip_runtime.h>
#include <hip/hip_bf16.h>

#define B_ 8
#define C_ 64
#define N_ 4096
#define K_ 20
#define O_ 64

typedef unsigned short ushort_t;
typedef __attribute__((ext_vector_type(8))) short bf16x8;
typedef __attribute__((ext_vector_type(16))) float f32x16;

constexpr float BN_EPS = 1e-5f;
constexpr float NEG = 0.2f;
constexpr int ROWS = B_ * N_;        // 32768
constexpr int M_TOT = ROWS * K_;     // 655360

__device__ __forceinline__ float readlane_f(float v, int src) {
  return __int_as_float(__builtin_amdgcn_readlane(__float_as_int(v), src));
}

// RNE float -> bf16 bits
__device__ __forceinline__ unsigned int bf16_rne(float v) {
  unsigned int u = __float_as_uint(v);
  return (u + 0x7FFFu + ((u >> 16) & 1u)) >> 16;
}

// ----------------------------------------------------------------------------
// ws layout (float elements):
//   y   : [0,        2097152)   y[b][n][o]  = xt[b,n,:] . W1[o,:]
//   z   : [2097152,  4194304)   z[b][n][o]  = xt[b,n,:] . (W2-W1)[o,:]
//   xx  : [4194304,  4227072)   xx[b][n]    = ||xt[b,n,:]||^2
//   idx : [4227072,  4882432)   (int) idx[b][n][k]
//   s1/s2/sc/sh : [4882432, 4882688)
//   xfh : [4882688,  5931264)   bf16 FRAGMENT-ORDER tiles, high split:
//                               [tile=n/32][chunk=c/8][m=n%32][t=c%8]
//   xfl : [5931264,  6979840)   mid split (same layout)
//   xfq : [6979840,  8028416)   low split
// Fragment-order => MFMA A/B loads are lane-contiguous: addr = tile*2048
//   + cc*512 + lane*8 (one dwordx4 = 1 KB dense per wave).
// ----------------------------------------------------------------------------

__global__ __launch_bounds__(256) void prep_kernel(const float* __restrict__ x,
                                                   const float* __restrict__ W,
                                                   float* __restrict__ y,
                                                   float* __restrict__ z,
                                                   float* __restrict__ xx,
                                                   ushort_t* __restrict__ xfh,
                                                   ushort_t* __restrict__ xfl,
                                                   ushort_t* __restrict__ xfq) {
  __shared__ float xt[64][65];  // [n_local][c]
  __shared__ float w1[64][65];  // [o][c]   = W[o][c]
  __shared__ float wd[64][65];  // [o][c]   = W[o][64+c] - W[o][c]
  const int b = blockIdx.x >> 6;
  const int n0 = (blockIdx.x & 63) << 6;
  const int tid = threadIdx.x;

  for (int rep = 0; rep < 16; ++rep) {
    int id = rep * 256 + tid;
    int cc = id >> 6, nl = id & 63;
    xt[nl][cc] = x[((b * 64 + cc) << 12) + n0 + nl];  // coalesced over nl
    int o = cc, c = nl;
    float a = W[o * 128 + c];
    float bb = W[o * 128 + 64 + c];
    w1[o][c] = a;
    wd[o][c] = bb - a;
  }
  __syncthreads();

  const int o = tid & 63;
  for (int nl = tid >> 6; nl < 64; nl += 4) {
    float ay = 0.f, az = 0.f;
#pragma unroll 8
    for (int c = 0; c < 64; ++c) {
      float v = xt[nl][c];
      ay = fmaf(v, w1[o][c], ay);
      az = fmaf(v, wd[o][c], az);
    }
    int gi = (((b << 12) + n0 + nl) << 6) + o;
    y[gi] = ay;
    z[gi] = az;
  }
  if (tid < 64) {
    float s = 0.f;
#pragma unroll 8
    for (int c = 0; c < 64; ++c) {
      float v = xt[tid][c];
      s = fmaf(v, v, s);
    }
    xx[(b << 12) + n0 + tid] = s;
  }

  // 3-way bf16 split, written in MFMA fragment order (tile/chunk/m/t)
  for (int rep = 0; rep < 16; ++rep) {
    int id = rep * 256 + tid;
    int nl = id >> 6, c = id & 63;
    float v = xt[nl][c];
    unsigned int hb = bf16_rne(v);
    float hf = __uint_as_float(hb << 16);
    float r1 = v - hf;
    unsigned int lb = bf16_rne(r1);
    float lf = __uint_as_float(lb << 16);
    unsigned int qb = bf16_rne(r1 - lf);
    const int n = n0 + nl;
    const size_t addr = ((size_t)((b << 7) + (n >> 5))) * 2048  // tile
                        + ((c >> 3) << 8)                        // chunk*256
                        + ((n & 31) << 3)                        // m*8
                        + (c & 7);                               // t
    xfh[addr] = (ushort_t)hb;
    xfl[addr] = (ushort_t)lb;
    xfq[addr] = (ushort_t)qb;
  }
}

// knn v13 = r8 (best structure, 385us) with fragment-order global layout.
// r8's wall was L1 transactions: [n][c] fragment loads had 128B lane stride
// -> 32 lines per dwordx4, ~770 lines/macro/wave (incl. A remat). Now A/B
// fragment loads are lane-contiguous (8 dense lines per load). Everything
// else byte-identical to r8: 6-product 3-way split MFMA schedule, verified
// C layout, Dld[32x132], two barriers, fresh-ballot selection -> identical
// neighbor sets.
__global__ __launch_bounds__(256, 3) void knn_kernel(const ushort_t* __restrict__ xfh,
                                                     const ushort_t* __restrict__ xfl,
                                                     const ushort_t* __restrict__ xfq,
                                                     const float* __restrict__ xx,
                                                     int* __restrict__ idx) {
  const int tid = threadIdx.x;
  const int w = tid >> 6;                 // wave 0..3
  const int lane = tid & 63;
  const int b = blockIdx.x >> 7;          // 128 strips per batch
  const int i0 = (blockIdx.x & 127) << 5; // 32-row strip
  const int mcol = lane & 31;
  const int half = lane >> 5;             // 0..1 (k-half)

  __shared__ float Dld[32 * 132];         // [row][128 j + pad]

  // A fragments: 3 splits x 4 c-chunks, lane-contiguous loads
  const size_t atile = ((size_t)blockIdx.x) * 2048;  // tile = b*128 + strip
  bf16x8 Ah[4], Al[4], Aq[4];
#pragma unroll
  for (int cc = 0; cc < 4; ++cc) {
    const size_t off = atile + (cc << 9) + (lane << 3);
    Ah[cc] = *(const bf16x8*)(xfh + off);
    Al[cc] = *(const bf16x8*)(xfl + off);
    Aq[cc] = *(const bf16x8*)(xfq + off);
  }

  float bv[8], T[8];
  int bi[8];
#pragma unroll
  for (int r = 0; r < 8; ++r) {
    bv[r] = __builtin_inff();
    T[r] = __builtin_inff();
    bi[r] = 0;
  }

  const float* xxb = xx + (b << 12);

  for (int t = 0; t < 32; ++t) {
    const int jb = t << 7;
    // this wave's 32-j tile: tile index (b*128 + jb/32 + w)
    const size_t btile = ((size_t)((b << 7) + (t << 2) + w)) * 2048;
    f32x16 acc;
#pragma unroll
    for (int q = 0; q < 16; ++q) acc[q] = 0.f;
#pragma unroll
    for (int cc = 0; cc < 4; ++cc) {
      const size_t off = btile + (cc << 9) + (lane << 3);
      bf16x8 Bh = *(const bf16x8*)(xfh + off);
      bf16x8 Bl = *(const bf16x8*)(xfl + off);
      bf16x8 Bq = *(const bf16x8*)(xfq + off);
      acc = __builtin_amdgcn_mfma_f32_32x32x16_bf16(Ah[cc], Bh, acc, 0, 0, 0);
      acc = __builtin_amdgcn_mfma_f32_32x32x16_bf16(Ah[cc], Bl, acc, 0, 0, 0);
      acc = __builtin_amdgcn_mfma_f32_32x32x16_bf16(Al[cc], Bh, acc, 0, 0, 0);
      acc = __builtin_amdgcn_mfma_f32_32x32x16_bf16(Ah[cc], Bq, acc, 0, 0, 0);
      acc = __builtin_amdgcn_mfma_f32_32x32x16_bf16(Aq[cc], Bh, acc, 0, 0, 0);
      acc = __builtin_amdgcn_mfma_f32_32x32x16_bf16(Al[cc], Bl, acc, 0, 0, 0);
    }
    const float xxv = xxb[jb + (w << 5) + mcol];
#pragma unroll
    for (int q = 0; q < 16; ++q) {
      int row = (q & 3) + ((q >> 2) << 3) + (half << 2);  // verified C layout
      Dld[row * 132 + (w << 5) + mcol] = fmaf(-2.f, acc[q], xxv);
    }
    __syncthreads();

    // selection: wave owns rows w*8 .. w*8+7, scans 128 j in two 64-lane segs
#pragma unroll
    for (int r = 0; r < 8; ++r) {
      const int row = (w << 3) + r;
#pragma unroll
      for (int seg = 0; seg < 2; ++seg) {
        float v = Dld[row * 132 + (seg << 6) + lane];
        int jlane = jb + (seg << 6) + lane;
        unsigned long long rem = 0xFFFFFFFFFFFFFFFFull;
        while (true) {
          unsigned long long m = __ballot(v < T[r]) & rem;
          if (!m) break;
          int src = __ffsll(m) - 1;
          rem &= ~(1ull << src);
          float cv = readlane_f(v, src);
          int cj = __builtin_amdgcn_readlane(jlane, src);
          unsigned long long le = __ballot(bv[r] <= cv) & 0xFFFFFull;
          int pos = __popcll(le);
          float pv = __shfl_up(bv[r], 1);
          int pi = __shfl_up(bi[r], 1);
          if (lane >= pos) {
            bool ins = (lane == pos);
            bv[r] = ins ? cv : pv;
            bi[r] = ins ? cj : pi;
          }
          T[r] = readlane_f(bv[r], K_ - 1);
        }
      }
    }
    __syncthreads();
  }

#pragma unroll
  for (int r = 0; r < 8; ++r) {
    if (lane < K_) idx[((b << 12) + i0 + (w << 3) + r) * K_ + lane] = bi[r];
  }
}

__global__ __launch_bounds__(256) void stats_kernel(const float* __restrict__ y,
                                                    const float* __restrict__ z,
                                                    const int* __restrict__ idx,
                                                    float* __restrict__ s1,
                                                    float* __restrict__ s2) {
  const int tid = threadIdx.x;
  const int o = tid & 63;
  const int r = tid >> 6;
  const int row0 = blockIdx.x << 6;  // 64 rows per block
  float a1 = 0.f, a2 = 0.f;
  for (int rl = r; rl < 64; rl += 4) {
    const int row = row0 + rl;
    const int b = row >> 12;
    const float zv = z[(row << 6) + o];
    const int* ip = idx + row * K_;
    const float* yb = y + ((size_t)b << 18);
    float s1r = 0.f;
#pragma unroll
    for (int k = 0; k < K_; ++k) {
      int j = ip[k];
      float h = yb[(j << 6) + o] + zv;
      s1r += h;
      a2 = fmaf(h, h, a2);
    }
    a1 += s1r;
  }
  __shared__ float r1[4][64];
  __shared__ float r2[4][64];
  r1[r][o] = a1;
  r2[r][o] = a2;
  __syncthreads();
  if (tid < 64) {
    float t1 = r1[0][tid] + r1[1][tid] + r1[2][tid] + r1[3][tid];
    float t2 = r2[0][tid] + r2[1][tid] + r2[2][tid] + r2[3][tid];
    atomicAdd(&s1[tid], t1);
    atomicAdd(&s2[tid], t2);
  }
}

__global__ void finalize_kernel(const float* __restrict__ s1,
                                const float* __restrict__ s2,
                                const float* __restrict__ gamma,
                                const float* __restrict__ beta,
                                float* __restrict__ sc,
                                float* __restrict__ sh) {
  int o = threadIdx.x;
  float mean = s1[o] / (float)M_TOT;
  float var = s2[o] / (float)M_TOT - mean * mean;
  float inv = 1.0f / sqrtf(var + BN_EPS);
  float s = gamma[o] * inv;
  sc[o] = s;
  sh[o] = beta[o] - mean * s;
}

__global__ __launch_bounds__(256) void out_kernel(const float* __restrict__ y,
                                                  const float* __restrict__ z,
                                                  const int* __restrict__ idx,
                                                  const float* __restrict__ sc,
                                                  const float* __restrict__ sh,
                                                  float* __restrict__ out) {
  __shared__ float til[64][65];  // [o][n_local]
  const int tid = threadIdx.x;
  const int b = blockIdx.x >> 6;
  const int n0 = (blockIdx.x & 63) << 6;
  const int o = tid & 63;
  const float s = sc[o];
  const float t = sh[o];
  const float* yb = y + ((size_t)b << 18);

  for (int nl = tid >> 6; nl < 64; nl += 4) {
    const int row = (b << 12) + n0 + nl;
    const float zv = z[(row << 6) + o];
    const int* ip = idx + row * K_;
    float m = -__builtin_inff();
#pragma unroll
    for (int k = 0; k < K_; ++k) {
      int j = ip[k];
      float h = yb[(j << 6) + o] + zv;
      float hn = fmaf(h, s, t);
      float a = hn >= 0.f ? hn : NEG * hn;
      m = fmaxf(m, a);
    }
    til[o][nl] = m;
  }
  __syncthreads();
  for (int rep = 0; rep < 16; ++rep) {
    int id = rep * 256 + tid;
    int oo = id >> 6, nl = id & 63;
    out[((size_t)((b << 6) + oo) << 12) + n0 + nl] = til[oo][nl];
  }
}

extern "C" void kernel_launch(void* const* d_in, const int* in_sizes, int n_in,
                              void* d_out, int out_size, void* d_ws, size_t ws_size,
                              hipStream_t stream) {
  const float* x = (const float*)d_in[0];
  const float* W = (const float*)d_in[1];
  const float* gamma = (const float*)d_in[2];
  const float* beta = (const float*)d_in[3];
  float* ws = (float*)d_ws;
  float* y = ws;
  float* z = ws + 2097152;
  float* xx = ws + 4194304;
  int* idxp = (int*)(ws + 4227072);
  float* s1 = ws + 4882432;
  float* s2 = ws + 4882496;
  float* sc = ws + 4882560;
  float* sh = ws + 4882624;
  ushort_t* xfh = (ushort_t*)(ws + 4882688);
  ushort_t* xfl = (ushort_t*)(ws + 5931264);
  ushort_t* xfq = (ushort_t*)(ws + 6979840);
  float* out = (float*)d_out;

  hipMemsetAsync(s1, 0, 2 * 64 * sizeof(float), stream);

  prep_kernel<<<512, 256, 0, stream>>>(x, W, y, z, xx, xfh, xfl, xfq);
  knn_kernel<<<ROWS / 32, 256, 0, stream>>>(xfh, xfl, xfq, xx, idxp);
  stats_kernel<<<512, 256, 0, stream>>>(y, z, idxp, s1, s2);
  finalize_kernel<<<1, 64, 0, stream>>>(s1, s2, gamma, beta, sc, sh);
  out_kernel<<<512, 256, 0, stream>>>(y, z, idxp, sc, sh, out);
}